// Round 4
// baseline (288.807 us; speedup 1.0000x reference)
//
#include <hip/hip_runtime.h>
#include <hip/hip_bf16.h>

// ModernBertAttention: B=4 S=2048 H=1024 NH=16 HD=64, rope theta=160000, f32 in/out.
// R4: attn = K-tile in registers (no sK), LDS 32KB -> 4-5 blocks/CU resident,
//     launch_bounds(256,4), setprio around MFMA clusters, XCD-chunked bh swizzle.
//     QKV gemm (+fused rope epilogue) / vtrans / out-proj unchanged from R3.

#define GLOBAL_AS __attribute__((address_space(1)))
#define LDS_AS    __attribute__((address_space(3)))

using f32x4 = __attribute__((ext_vector_type(4))) float;
using s16x8 = __attribute__((ext_vector_type(8))) short;

__device__ __forceinline__ void gld_lds16(const void* g, void* l) {
  __builtin_amdgcn_global_load_lds((const GLOBAL_AS void*)g, (LDS_AS void*)l, 16, 0, 0);
}

__device__ __forceinline__ unsigned short f2bf(float f) {
  unsigned int u = __float_as_uint(f);
  u = (u + 0x7fffu + ((u >> 16) & 1u)) >> 16;   // RNE
  return (unsigned short)u;
}
__device__ __forceinline__ unsigned int cvt_pk_bf16(float lo, float hi) {
  unsigned int r;
  asm("v_cvt_pk_bf16_f32 %0, %1, %2" : "=v"(r) : "v"(lo), "v"(hi));
  return r;
}

// ---------------- merged f32 -> bf16 convert (4 elems/thread) ----------------
__global__ __launch_bounds__(256) void cvt_all_kernel(const float* __restrict__ h,
                                                      const float* __restrict__ wq,
                                                      const float* __restrict__ wo,
                                                      unsigned short* __restrict__ hb,
                                                      unsigned short* __restrict__ wqb,
                                                      unsigned short* __restrict__ wob) {
  int b = blockIdx.x;
  const float* src; unsigned short* dst; int i;
  if (b < 8192)       { src = h;  dst = hb;  i = b * 256 + threadIdx.x; }
  else if (b < 11264) { src = wq; dst = wqb; i = (b - 8192) * 256 + threadIdx.x; }
  else                { src = wo; dst = wob; i = (b - 11264) * 256 + threadIdx.x; }
  float4 v = ((const float4*)src)[i];
  ushort4 o;
  o.x = f2bf(v.x); o.y = f2bf(v.y); o.z = f2bf(v.z); o.w = f2bf(v.w);
  ((ushort4*)dst)[i] = o;
}

// ---------------- rope cos/sin table: idx = (b*2048+s)*32 + d ----------------
__global__ __launch_bounds__(256) void rope_table_kernel(const int* __restrict__ pos,
                                                         float* __restrict__ ctab,
                                                         float* __restrict__ stab) {
  int idx = blockIdx.x * 256 + threadIdx.x;   // B*S*32 total
  int d = idx & 31;
  int bs = idx >> 5;
  float p = (float)pos[bs];
  float inv = exp2f(-(float)d * 0.5402410118609203f);  // theta^(-d/32)
  float f = p * inv;
  ctab[idx] = cosf(f);
  stab[idx] = sinf(f);
}

// ---------------- GEMM C[m,n] = sum_k A[m,k]*B[n,k], bf16 in, 128x128 tile, BK=64 ----------------
// MODE 1: f32 C store. MODE 2: fused QKV epilogue (rope -> Qr/Kr, V -> vbuf).
template<int MODE>
__global__ __launch_bounds__(256) void gemm_bt_kernel(const unsigned short* __restrict__ A,
                                                      const unsigned short* __restrict__ Bm,
                                                      void* __restrict__ C, int N, int K,
                                                      const float* __restrict__ ctab,
                                                      const float* __restrict__ stab,
                                                      unsigned short* __restrict__ Qr,
                                                      unsigned short* __restrict__ Kr,
                                                      unsigned short* __restrict__ vbuf) {
  __shared__ char sA[16384];   // 128 rows x 64 bf16 (128B rows), XOR-swizzled (row&7)<<4
  __shared__ char sB[16384];
  const int tid  = threadIdx.x;
  const int lane = tid & 63, w = tid >> 6;
  const int g = lane >> 4, c = lane & 15;
  const int wr = w >> 1, wc = w & 1;
  const int m0 = blockIdx.x * 128, n0 = blockIdx.y * 128;
  const char* Ab = (const char*)A;
  const char* Bb = (const char*)Bm;

  f32x4 acc[4][4] = {};
  for (int k0 = 0; k0 < K; k0 += 64) {
    __syncthreads();
#pragma unroll
    for (int rr = 0; rr < 4; ++rr) {
      int o = tid * 16 + rr * 4096;
      int row = o >> 7;
      int col = (o & 127) ^ ((row & 7) << 4);   // pre-swizzled source column
      gld_lds16(Ab + ((size_t)(m0 + row) * K + k0) * 2 + col, sA + o);
      gld_lds16(Bb + ((size_t)(n0 + row) * K + k0) * 2 + col, sB + o);
    }
    __syncthreads();
#pragma unroll
    for (int ks = 0; ks < 2; ++ks) {
      s16x8 af[4], bfr[4];
#pragma unroll
      for (int i = 0; i < 4; ++i) {
        int row = 64 * wr + 16 * i + c;
        af[i] = *(const s16x8*)(sA + ((row * 128 + ks * 64 + g * 16) ^ ((row & 7) << 4)));
      }
#pragma unroll
      for (int j = 0; j < 4; ++j) {
        int row = 64 * wc + 16 * j + c;
        bfr[j] = *(const s16x8*)(sB + ((row * 128 + ks * 64 + g * 16) ^ ((row & 7) << 4)));
      }
#pragma unroll
      for (int i = 0; i < 4; ++i)
#pragma unroll
        for (int j = 0; j < 4; ++j)
          acc[i][j] = __builtin_amdgcn_mfma_f32_16x16x32_bf16(af[i], bfr[j], acc[i][j], 0, 0, 0);
    }
  }

  if (MODE == 1) {
#pragma unroll
    for (int i = 0; i < 4; ++i)
#pragma unroll
      for (int j = 0; j < 4; ++j)
#pragma unroll
        for (int r = 0; r < 4; ++r) {
          int m = m0 + 64 * wr + 16 * i + 4 * g + r;
          int n = n0 + 64 * wc + 16 * j + c;
          ((float*)C)[(size_t)m * N + n] = acc[i][j][r];
        }
  } else {
    const int t = blockIdx.y;   // 0..7 Q, 8..15 K, 16..23 V
    if (t < 16) {
      unsigned short* dstb = (t < 8) ? Qr : Kr;
      const float qs = (t < 8) ? 0.18033688011112042f : 1.0f;  // SCALE*log2(e) on Q
      const int h = 2 * (t & 7) + wc;
#pragma unroll
      for (int i = 0; i < 4; ++i)
#pragma unroll
        for (int r = 0; r < 4; ++r) {
          int m = m0 + 64 * wr + 16 * i + 4 * g + r;
          int b = m >> 11, s = m & 2047;
          unsigned short* drow = dstb + ((size_t)(b * 16 + h) * 2048 + s) * 64;
#pragma unroll
          for (int j = 0; j < 2; ++j) {
            int d = 16 * j + c;
            float co = ctab[(size_t)m * 32 + d];
            float si = stab[(size_t)m * 32 + d];
            float x1 = acc[i][j][r], x2 = acc[i][j + 2][r];
            drow[d]      = f2bf((x1 * co - x2 * si) * qs);
            drow[d + 32] = f2bf((x2 * co + x1 * si) * qs);
          }
        }
    } else {
#pragma unroll
      for (int i = 0; i < 4; ++i)
#pragma unroll
        for (int j = 0; j < 4; ++j)
#pragma unroll
          for (int r = 0; r < 4; ++r) {
            int m = m0 + 64 * wr + 16 * i + 4 * g + r;
            int n = (t - 16) * 128 + 64 * wc + 16 * j + c;
            vbuf[(size_t)m * 1024 + n] = f2bf(acc[i][j][r]);
          }
    }
  }
}

// ---------------- V transpose: vbuf (B*S,1024) -> Vt (B,NH,64,S) ----------------
__global__ __launch_bounds__(256) void vtrans_kernel(const unsigned short* __restrict__ vbuf,
                                                     unsigned short* __restrict__ Vt) {
  __shared__ unsigned short tile[64][80];
  int bid = blockIdx.x;                      // b*16*32 + h*32 + st
  int st = bid & 31, h = (bid >> 5) & 15, b = bid >> 9;
  int s0 = st * 64;
  int t = threadIdx.x;
  {
    int row = t >> 2, part = t & 3;
    const unsigned short* src = vbuf + ((size_t)(b * 2048 + s0 + row)) * 1024 + h * 64 + part * 16;
    uint4 v0 = *(const uint4*)(src);
    uint4 v1 = *(const uint4*)(src + 8);
    *(uint4*)&tile[row][part * 16]     = v0;
    *(uint4*)&tile[row][part * 16 + 8] = v1;
  }
  __syncthreads();
  {
    int d = t >> 2, sp = t & 3;
    unsigned short vals[16];
#pragma unroll
    for (int i = 0; i < 16; ++i) vals[i] = tile[sp * 16 + i][d];
    unsigned short* dst = Vt + ((size_t)(b * 16 + h) * 64 + d) * 2048 + s0 + sp * 16;
    *(uint4*)(dst)     = ((const uint4*)vals)[0];
    *(uint4*)(dst + 8) = ((const uint4*)vals)[1];
  }
}

// ---------------- flash attention: 128 q-rows/block, 4 waves x 2 q-groups ----------------
// K tile in registers (per-lane global loads, 1-tile prefetch); V dbuf in LDS;
// fixed m=0 exp2 softmax; setprio around MFMA clusters; LDS = 32KB.
__global__ __launch_bounds__(256, 4) void attn_kernel(const unsigned short* __restrict__ Q,
                                                      const unsigned short* __restrict__ Kr,
                                                      const unsigned short* __restrict__ Vt,
                                                      unsigned short* __restrict__ Ctx) {
  __shared__ char sV[2][8192];   // 64 d rows x 128B (V^T tile), swizzle (row&7)<<4
  __shared__ char sP[16384];     // 4 waves x 2 groups x 16 q rows x 128B
  const int tid  = threadIdx.x;
  const int lane = tid & 63, w = tid >> 6;
  const int g = lane >> 4, c = lane & 15;
  // XCD-chunked swizzle: each XCD owns 8 consecutive bh (K+V = 4MB = one L2)
  int lin = blockIdx.x + 16 * blockIdx.y;            // grid (16, 64)
  int eff = (lin & 7) * 128 + (lin >> 3);
  const int bh = eff >> 4;
  const int q0 = (eff & 15) * 128;
  const char* kh = (const char*)(Kr + (size_t)bh * 2048 * 64);
  const char* vh = (const char*)(Vt + (size_t)bh * 64 * 2048);

  // Q fragments: lane holds Q[q=q0+32w+16u+c][d=8g..8g+7 (+64*ks)]
  s16x8 qf[2][2];
#pragma unroll
  for (int u = 0; u < 2; ++u) {
    const char* qrow = (const char*)(Q + (size_t)bh * 2048 * 64) + (size_t)(q0 + 32 * w + 16 * u + c) * 128;
    qf[u][0] = *(const s16x8*)(qrow + g * 16);
    qf[u][1] = *(const s16x8*)(qrow + 64 + g * 16);
  }

  // K fragments in registers: kreg[j][ks] = K[kv=16j+c][d=8g.. +64ks] (A-operand)
  const char* kbase = kh + (size_t)c * 128 + g * 16;
  s16x8 kreg[4][2];
#pragma unroll
  for (int j = 0; j < 4; ++j)
#pragma unroll
    for (int ks = 0; ks < 2; ++ks)
      kreg[j][ks] = *(const s16x8*)(kbase + j * 2048 + ks * 64);

  // stage V tile 0 into buffer 0
#pragma unroll
  for (int rr = 0; rr < 2; ++rr) {
    int o = tid * 16 + rr * 4096;
    int l = o ^ (((o >> 7) & 7) << 4);
    gld_lds16(vh + (size_t)(o >> 7) * 4096 + (l & 127), sV[0] + o);
  }

  float l_run[2] = {0.f, 0.f};
  f32x4 o_acc[2][4] = {};
  char* pw0 = sP + w * 4096;
  char* pw1 = pw0 + 2048;

  for (int it = 0; it < 32; ++it) {
    __syncthreads();   // V(it) resident (vmcnt drained); other buffer free
    const int cur = it & 1;
    if (it + 1 < 32) {                   // stage V(it+1)
      int kvn = (it + 1) * 64;
#pragma unroll
      for (int rr = 0; rr < 2; ++rr) {
        int o = tid * 16 + rr * 4096;
        int l = o ^ (((o >> 7) & 7) << 4);
        gld_lds16(vh + (size_t)(o >> 7) * 4096 + kvn * 2 + (l & 127), sV[cur ^ 1] + o);
      }
    }

    // ---- q-group 0: QK^T + softmax + P-write ----
    __builtin_amdgcn_s_setprio(1);
    f32x4 sc0[4] = {};
#pragma unroll
    for (int j = 0; j < 4; ++j)
#pragma unroll
      for (int ks = 0; ks < 2; ++ks)
        sc0[j] = __builtin_amdgcn_mfma_f32_16x16x32_bf16(kreg[j][ks], qf[0][ks], sc0[j], 0, 0, 0);
    __builtin_amdgcn_s_setprio(0);
    {
      float rs = 0.f;
#pragma unroll
      for (int j = 0; j < 4; ++j) {
        float e0 = __builtin_amdgcn_exp2f(sc0[j][0]);
        float e1 = __builtin_amdgcn_exp2f(sc0[j][1]);
        float e2 = __builtin_amdgcn_exp2f(sc0[j][2]);
        float e3 = __builtin_amdgcn_exp2f(sc0[j][3]);
        rs += (e0 + e1) + (e2 + e3);
        uint2 pk;
        pk.x = cvt_pk_bf16(e0, e1);
        pk.y = cvt_pk_bf16(e2, e3);
        *(uint2*)(pw0 + ((c * 128 + 32 * j + 8 * g) ^ ((c & 7) << 4))) = pk;
      }
      l_run[0] += rs;
    }

    // ---- q-group 1: QK^T + softmax + P-write ----
    __builtin_amdgcn_s_setprio(1);
    f32x4 sc1[4] = {};
#pragma unroll
    for (int j = 0; j < 4; ++j)
#pragma unroll
      for (int ks = 0; ks < 2; ++ks)
        sc1[j] = __builtin_amdgcn_mfma_f32_16x16x32_bf16(kreg[j][ks], qf[1][ks], sc1[j], 0, 0, 0);
    __builtin_amdgcn_s_setprio(0);

    // prefetch K(it+1) into kreg (after last kreg use; drains at next barrier)
    if (it + 1 < 32) {
      const char* kb2 = kbase + (size_t)(it + 1) * 8192;
#pragma unroll
      for (int j = 0; j < 4; ++j)
#pragma unroll
        for (int ks = 0; ks < 2; ++ks)
          kreg[j][ks] = *(const s16x8*)(kb2 + j * 2048 + ks * 64);
    }

    {
      float rs = 0.f;
#pragma unroll
      for (int j = 0; j < 4; ++j) {
        float e0 = __builtin_amdgcn_exp2f(sc1[j][0]);
        float e1 = __builtin_amdgcn_exp2f(sc1[j][1]);
        float e2 = __builtin_amdgcn_exp2f(sc1[j][2]);
        float e3 = __builtin_amdgcn_exp2f(sc1[j][3]);
        rs += (e0 + e1) + (e2 + e3);
        uint2 pk;
        pk.x = cvt_pk_bf16(e0, e1);
        pk.y = cvt_pk_bf16(e2, e3);
        *(uint2*)(pw1 + ((c * 128 + 32 * j + 8 * g) ^ ((c & 7) << 4))) = pk;
      }
      l_run[1] += rs;
    }
    asm volatile("s_waitcnt lgkmcnt(0)" ::: "memory");   // P writes visible

    // ---- PV: vb shared across both q-groups ----
    __builtin_amdgcn_s_setprio(1);
#pragma unroll
    for (int ns = 0; ns < 2; ++ns) {
      s16x8 pa0 = *(const s16x8*)(pw0 + ((c * 128 + ns * 64 + g * 16) ^ ((c & 7) << 4)));
      s16x8 pa1 = *(const s16x8*)(pw1 + ((c * 128 + ns * 64 + g * 16) ^ ((c & 7) << 4)));
#pragma unroll
      for (int dj = 0; dj < 4; ++dj) {
        int row = 16 * dj + c;
        s16x8 vb = *(const s16x8*)(sV[cur] + ((row * 128 + ns * 64 + g * 16) ^ ((c & 7) << 4)));
        o_acc[0][dj] = __builtin_amdgcn_mfma_f32_16x16x32_bf16(pa0, vb, o_acc[0][dj], 0, 0, 0);
        o_acc[1][dj] = __builtin_amdgcn_mfma_f32_16x16x32_bf16(pa1, vb, o_acc[1][dj], 0, 0, 0);
      }
    }
    __builtin_amdgcn_s_setprio(0);
  }

  // epilogue: reduce lane-partial l across g-groups, normalize, store ctx bf16
  const int b = bh >> 4, h = bh & 15;
#pragma unroll
  for (int u = 0; u < 2; ++u) {
    float l = l_run[u];
    l += __shfl_xor(l, 16);
    l += __shfl_xor(l, 32);
#pragma unroll
    for (int r = 0; r < 4; ++r) {
      float lr = __shfl(l, (lane & 48) | (4 * g + r));
      float inv = 1.f / lr;
      int srow = q0 + 32 * w + 16 * u + 4 * g + r;
      unsigned short* crow = Ctx + ((size_t)(b * 2048 + srow)) * 1024 + h * 64;
#pragma unroll
      for (int dj = 0; dj < 4; ++dj)
        crow[16 * dj + c] = f2bf(o_acc[u][dj][r] * inv);
    }
  }
}

extern "C" void kernel_launch(void* const* d_in, const int* in_sizes, int n_in,
                              void* d_out, int out_size, void* d_ws, size_t ws_size,
                              hipStream_t stream) {
  const float* hidden = (const float*)d_in[0];   // (4,2048,1024) f32
  const int*   pos    = (const int*)d_in[1];     // (4,2048) i32
  const float* wqkv   = (const float*)d_in[2];   // (3072,1024) f32
  const float* wo     = (const float*)d_in[3];   // (1024,1024) f32

  char* ws = (char*)d_ws;
  unsigned short* hbf  = (unsigned short*)(ws);                 // 16,777,216 B
  unsigned short* wqbf = (unsigned short*)(ws + 16777216);      //  6,291,456
  unsigned short* wobf = (unsigned short*)(ws + 23068672);      //  2,097,152
  unsigned short* vbuf = (unsigned short*)(ws + 25165824);      // 16,777,216
  unsigned short* Qr   = (unsigned short*)(ws + 41943040);      // 16,777,216
  unsigned short* Kr   = (unsigned short*)(ws + 58720256);      // 16,777,216
  unsigned short* Vt   = (unsigned short*)(ws + 75497472);      // 16,777,216
  unsigned short* ctx  = (unsigned short*)(ws + 92274688);      // 16,777,216
  float*          ctab = (float*)(ws + 109051904);              //  1,048,576
  float*          stab = (float*)(ws + 110100480);              //  1,048,576
  // total: 111,149,056 B

  cvt_all_kernel<<<12288, 256, 0, stream>>>(hidden, wqkv, wo, hbf, wqbf, wobf);
  rope_table_kernel<<<1024, 256, 0, stream>>>(pos, ctab, stab);

  dim3 gq(64, 24);
  gemm_bt_kernel<2><<<gq, 256, 0, stream>>>(hbf, wqbf, nullptr, 3072, 1024,
                                            ctab, stab, Qr, Kr, vbuf);

  vtrans_kernel<<<2048, 256, 0, stream>>>(vbuf, Vt);

  dim3 ga(16, 64);
  attn_kernel<<<ga, 256, 0, stream>>>(Qr, Kr, Vt, ctx);

  dim3 go(64, 8);
  gemm_bt_kernel<1><<<go, 256, 0, stream>>>(ctx, wobf, d_out, 1024, 1024,
                                            nullptr, nullptr, nullptr, nullptr, nullptr);
}

// Round 5
// 213.285 us; speedup vs baseline: 1.3541x; 1.3541x over previous
//
#include <hip/hip_runtime.h>
#include <hip/hip_bf16.h>

// ModernBertAttention: B=4 S=2048 H=1024 NH=16 HD=64, rope theta=160000, f32 in/out.
// R5: attn reverted to R3 structure (K+V dbuf in LDS; R4's K-in-reg spilled to scratch).
//     sP shrunk 16KB->8KB via per-q-group PV split => LDS 40KB => 4 blocks/CU resident.
//     Keeps: fixed m=0 exp2 softmax, cvt_pk P path, XCD-chunked swizzle, setprio, cvt_all.

#define GLOBAL_AS __attribute__((address_space(1)))
#define LDS_AS    __attribute__((address_space(3)))

using f32x4 = __attribute__((ext_vector_type(4))) float;
using s16x8 = __attribute__((ext_vector_type(8))) short;

__device__ __forceinline__ void gld_lds16(const void* g, void* l) {
  __builtin_amdgcn_global_load_lds((const GLOBAL_AS void*)g, (LDS_AS void*)l, 16, 0, 0);
}

__device__ __forceinline__ unsigned short f2bf(float f) {
  unsigned int u = __float_as_uint(f);
  u = (u + 0x7fffu + ((u >> 16) & 1u)) >> 16;   // RNE
  return (unsigned short)u;
}
__device__ __forceinline__ unsigned int cvt_pk_bf16(float lo, float hi) {
  unsigned int r;
  asm("v_cvt_pk_bf16_f32 %0, %1, %2" : "=v"(r) : "v"(lo), "v"(hi));
  return r;
}

// ---------------- merged f32 -> bf16 convert (4 elems/thread) ----------------
__global__ __launch_bounds__(256) void cvt_all_kernel(const float* __restrict__ h,
                                                      const float* __restrict__ wq,
                                                      const float* __restrict__ wo,
                                                      unsigned short* __restrict__ hb,
                                                      unsigned short* __restrict__ wqb,
                                                      unsigned short* __restrict__ wob) {
  int b = blockIdx.x;
  const float* src; unsigned short* dst; int i;
  if (b < 8192)       { src = h;  dst = hb;  i = b * 256 + threadIdx.x; }
  else if (b < 11264) { src = wq; dst = wqb; i = (b - 8192) * 256 + threadIdx.x; }
  else                { src = wo; dst = wob; i = (b - 11264) * 256 + threadIdx.x; }
  float4 v = ((const float4*)src)[i];
  ushort4 o;
  o.x = f2bf(v.x); o.y = f2bf(v.y); o.z = f2bf(v.z); o.w = f2bf(v.w);
  ((ushort4*)dst)[i] = o;
}

// ---------------- rope cos/sin table: idx = (b*2048+s)*32 + d ----------------
__global__ __launch_bounds__(256) void rope_table_kernel(const int* __restrict__ pos,
                                                         float* __restrict__ ctab,
                                                         float* __restrict__ stab) {
  int idx = blockIdx.x * 256 + threadIdx.x;   // B*S*32 total
  int d = idx & 31;
  int bs = idx >> 5;
  float p = (float)pos[bs];
  float inv = exp2f(-(float)d * 0.5402410118609203f);  // theta^(-d/32)
  float f = p * inv;
  ctab[idx] = cosf(f);
  stab[idx] = sinf(f);
}

// ---------------- GEMM C[m,n] = sum_k A[m,k]*B[n,k], bf16 in, 128x128 tile, BK=64 ----------------
// MODE 1: f32 C store. MODE 2: fused QKV epilogue (rope -> Qr/Kr, V -> vbuf).
template<int MODE>
__global__ __launch_bounds__(256) void gemm_bt_kernel(const unsigned short* __restrict__ A,
                                                      const unsigned short* __restrict__ Bm,
                                                      void* __restrict__ C, int N, int K,
                                                      const float* __restrict__ ctab,
                                                      const float* __restrict__ stab,
                                                      unsigned short* __restrict__ Qr,
                                                      unsigned short* __restrict__ Kr,
                                                      unsigned short* __restrict__ vbuf) {
  __shared__ char sA[16384];   // 128 rows x 64 bf16 (128B rows), XOR-swizzled (row&7)<<4
  __shared__ char sB[16384];
  const int tid  = threadIdx.x;
  const int lane = tid & 63, w = tid >> 6;
  const int g = lane >> 4, c = lane & 15;
  const int wr = w >> 1, wc = w & 1;
  const int m0 = blockIdx.x * 128, n0 = blockIdx.y * 128;
  const char* Ab = (const char*)A;
  const char* Bb = (const char*)Bm;

  f32x4 acc[4][4] = {};
  for (int k0 = 0; k0 < K; k0 += 64) {
    __syncthreads();
#pragma unroll
    for (int rr = 0; rr < 4; ++rr) {
      int o = tid * 16 + rr * 4096;
      int row = o >> 7;
      int col = (o & 127) ^ ((row & 7) << 4);   // pre-swizzled source column
      gld_lds16(Ab + ((size_t)(m0 + row) * K + k0) * 2 + col, sA + o);
      gld_lds16(Bb + ((size_t)(n0 + row) * K + k0) * 2 + col, sB + o);
    }
    __syncthreads();
#pragma unroll
    for (int ks = 0; ks < 2; ++ks) {
      s16x8 af[4], bfr[4];
#pragma unroll
      for (int i = 0; i < 4; ++i) {
        int row = 64 * wr + 16 * i + c;
        af[i] = *(const s16x8*)(sA + ((row * 128 + ks * 64 + g * 16) ^ ((row & 7) << 4)));
      }
#pragma unroll
      for (int j = 0; j < 4; ++j) {
        int row = 64 * wc + 16 * j + c;
        bfr[j] = *(const s16x8*)(sB + ((row * 128 + ks * 64 + g * 16) ^ ((row & 7) << 4)));
      }
#pragma unroll
      for (int i = 0; i < 4; ++i)
#pragma unroll
        for (int j = 0; j < 4; ++j)
          acc[i][j] = __builtin_amdgcn_mfma_f32_16x16x32_bf16(af[i], bfr[j], acc[i][j], 0, 0, 0);
    }
  }

  if (MODE == 1) {
#pragma unroll
    for (int i = 0; i < 4; ++i)
#pragma unroll
      for (int j = 0; j < 4; ++j)
#pragma unroll
        for (int r = 0; r < 4; ++r) {
          int m = m0 + 64 * wr + 16 * i + 4 * g + r;
          int n = n0 + 64 * wc + 16 * j + c;
          ((float*)C)[(size_t)m * N + n] = acc[i][j][r];
        }
  } else {
    const int t = blockIdx.y;   // 0..7 Q, 8..15 K, 16..23 V
    if (t < 16) {
      unsigned short* dstb = (t < 8) ? Qr : Kr;
      const float qs = (t < 8) ? 0.18033688011112042f : 1.0f;  // SCALE*log2(e) on Q
      const int h = 2 * (t & 7) + wc;
#pragma unroll
      for (int i = 0; i < 4; ++i)
#pragma unroll
        for (int r = 0; r < 4; ++r) {
          int m = m0 + 64 * wr + 16 * i + 4 * g + r;
          int b = m >> 11, s = m & 2047;
          unsigned short* drow = dstb + ((size_t)(b * 16 + h) * 2048 + s) * 64;
#pragma unroll
          for (int j = 0; j < 2; ++j) {
            int d = 16 * j + c;
            float co = ctab[(size_t)m * 32 + d];
            float si = stab[(size_t)m * 32 + d];
            float x1 = acc[i][j][r], x2 = acc[i][j + 2][r];
            drow[d]      = f2bf((x1 * co - x2 * si) * qs);
            drow[d + 32] = f2bf((x2 * co + x1 * si) * qs);
          }
        }
    } else {
#pragma unroll
      for (int i = 0; i < 4; ++i)
#pragma unroll
        for (int j = 0; j < 4; ++j)
#pragma unroll
          for (int r = 0; r < 4; ++r) {
            int m = m0 + 64 * wr + 16 * i + 4 * g + r;
            int n = (t - 16) * 128 + 64 * wc + 16 * j + c;
            vbuf[(size_t)m * 1024 + n] = f2bf(acc[i][j][r]);
          }
    }
  }
}

// ---------------- V transpose: vbuf (B*S,1024) -> Vt (B,NH,64,S) ----------------
__global__ __launch_bounds__(256) void vtrans_kernel(const unsigned short* __restrict__ vbuf,
                                                     unsigned short* __restrict__ Vt) {
  __shared__ unsigned short tile[64][80];
  int bid = blockIdx.x;                      // b*16*32 + h*32 + st
  int st = bid & 31, h = (bid >> 5) & 15, b = bid >> 9;
  int s0 = st * 64;
  int t = threadIdx.x;
  {
    int row = t >> 2, part = t & 3;
    const unsigned short* src = vbuf + ((size_t)(b * 2048 + s0 + row)) * 1024 + h * 64 + part * 16;
    uint4 v0 = *(const uint4*)(src);
    uint4 v1 = *(const uint4*)(src + 8);
    *(uint4*)&tile[row][part * 16]     = v0;
    *(uint4*)&tile[row][part * 16 + 8] = v1;
  }
  __syncthreads();
  {
    int d = t >> 2, sp = t & 3;
    unsigned short vals[16];
#pragma unroll
    for (int i = 0; i < 16; ++i) vals[i] = tile[sp * 16 + i][d];
    unsigned short* dst = Vt + ((size_t)(b * 16 + h) * 64 + d) * 2048 + s0 + sp * 16;
    *(uint4*)(dst)     = ((const uint4*)vals)[0];
    *(uint4*)(dst + 8) = ((const uint4*)vals)[1];
  }
}

// ---------------- flash attention: 128 q-rows/block, 4 waves x 2 q-groups ----------------
// R3 structure: K+V double-buffered in LDS via global_load_lds; fixed m=0 exp2 softmax.
// sP is 2KB/wave (8KB), reused across the two q-groups (PV split per group).
// LDS = 40KB -> 4 blocks/CU resident (grid = 1024 = 4/CU, zero tail).
__global__ __launch_bounds__(256, 3) void attn_kernel(const unsigned short* __restrict__ Q,
                                                      const unsigned short* __restrict__ Kr,
                                                      const unsigned short* __restrict__ Vt,
                                                      unsigned short* __restrict__ Ctx) {
  __shared__ char sK[2][8192];   // 64 kv rows x 128B, swizzle (row&7)<<4
  __shared__ char sV[2][8192];   // 64 d rows x 128B (V^T tile)
  __shared__ char sP[8192];      // 4 waves x 16 q rows x 128B (shared across q-groups)
  const int tid  = threadIdx.x;
  const int lane = tid & 63, w = tid >> 6;
  const int g = lane >> 4, c = lane & 15;
  // XCD-chunked swizzle: each XCD owns 8 consecutive bh (K+V ~4MB = one L2)
  int lin = blockIdx.x + 16 * blockIdx.y;            // grid (16, 64)
  int eff = (lin & 7) * 128 + (lin >> 3);
  const int bh = eff >> 4;
  const int q0 = (eff & 15) * 128;
  const char* kh = (const char*)(Kr + (size_t)bh * 2048 * 64);
  const char* vh = (const char*)(Vt + (size_t)bh * 64 * 2048);

  // Q fragments: lane holds Q[q=q0+32w+16u+c][d=8g..8g+7 (+64*ks)]
  s16x8 qf[2][2];
#pragma unroll
  for (int u = 0; u < 2; ++u) {
    const char* qrow = (const char*)(Q + (size_t)bh * 2048 * 64) + (size_t)(q0 + 32 * w + 16 * u + c) * 128;
    qf[u][0] = *(const s16x8*)(qrow + g * 16);
    qf[u][1] = *(const s16x8*)(qrow + 64 + g * 16);
  }

  // prologue: stage K,V tile 0 into buffer 0
#pragma unroll
  for (int rr = 0; rr < 2; ++rr) {
    int o = tid * 16 + rr * 4096;
    int l = o ^ (((o >> 7) & 7) << 4);
    gld_lds16(kh + l, sK[0] + o);
    gld_lds16(vh + (size_t)(o >> 7) * 4096 + (l & 127), sV[0] + o);
  }

  float l_run[2] = {0.f, 0.f};
  f32x4 o_acc[2][4] = {};
  char* pw = sP + w * 2048;

  for (int it = 0; it < 32; ++it) {
    __syncthreads();   // K/V(it) resident (vmcnt drained); other buffer free
    const int cur = it & 1;
    if (it + 1 < 32) {                   // stage K/V(it+1)
      int kvn = (it + 1) * 64;
#pragma unroll
      for (int rr = 0; rr < 2; ++rr) {
        int o = tid * 16 + rr * 4096;
        int l = o ^ (((o >> 7) & 7) << 4);
        gld_lds16(kh + (size_t)kvn * 128 + l, sK[cur ^ 1] + o);
        gld_lds16(vh + (size_t)(o >> 7) * 4096 + kvn * 2 + (l & 127), sV[cur ^ 1] + o);
      }
    }

    // QK^T swapped for both q-groups (kb fragments shared)
    __builtin_amdgcn_s_setprio(1);
    f32x4 sc0[4] = {}, sc1[4] = {};
#pragma unroll
    for (int j = 0; j < 4; ++j) {
      int row = 16 * j + c;
#pragma unroll
      for (int ks = 0; ks < 2; ++ks) {
        s16x8 kb = *(const s16x8*)(sK[cur] + ((row * 128 + ks * 64 + g * 16) ^ ((c & 7) << 4)));
        sc0[j] = __builtin_amdgcn_mfma_f32_16x16x32_bf16(kb, qf[0][ks], sc0[j], 0, 0, 0);
        sc1[j] = __builtin_amdgcn_mfma_f32_16x16x32_bf16(kb, qf[1][ks], sc1[j], 0, 0, 0);
      }
    }
    __builtin_amdgcn_s_setprio(0);

    // ---- q-group 0: softmax -> P -> PV ----
    {
      float rs = 0.f;
#pragma unroll
      for (int j = 0; j < 4; ++j) {
        float e0 = __builtin_amdgcn_exp2f(sc0[j][0]);
        float e1 = __builtin_amdgcn_exp2f(sc0[j][1]);
        float e2 = __builtin_amdgcn_exp2f(sc0[j][2]);
        float e3 = __builtin_amdgcn_exp2f(sc0[j][3]);
        rs += (e0 + e1) + (e2 + e3);
        uint2 pk;
        pk.x = cvt_pk_bf16(e0, e1);
        pk.y = cvt_pk_bf16(e2, e3);
        *(uint2*)(pw + ((c * 128 + 32 * j + 8 * g) ^ ((c & 7) << 4))) = pk;
      }
      l_run[0] += rs;
    }
    asm volatile("s_waitcnt lgkmcnt(0)" ::: "memory");   // P writes visible
    __builtin_amdgcn_s_setprio(1);
#pragma unroll
    for (int ns = 0; ns < 2; ++ns) {
      s16x8 pa = *(const s16x8*)(pw + ((c * 128 + ns * 64 + g * 16) ^ ((c & 7) << 4)));
#pragma unroll
      for (int dj = 0; dj < 4; ++dj) {
        int row = 16 * dj + c;
        s16x8 vb = *(const s16x8*)(sV[cur] + ((row * 128 + ns * 64 + g * 16) ^ ((c & 7) << 4)));
        o_acc[0][dj] = __builtin_amdgcn_mfma_f32_16x16x32_bf16(pa, vb, o_acc[0][dj], 0, 0, 0);
      }
    }
    __builtin_amdgcn_s_setprio(0);
    asm volatile("" ::: "memory");   // keep group-1 P writes below group-0 pa reads

    // ---- q-group 1: softmax -> P -> PV (reuses pw; same-wave DS ordering) ----
    {
      float rs = 0.f;
#pragma unroll
      for (int j = 0; j < 4; ++j) {
        float e0 = __builtin_amdgcn_exp2f(sc1[j][0]);
        float e1 = __builtin_amdgcn_exp2f(sc1[j][1]);
        float e2 = __builtin_amdgcn_exp2f(sc1[j][2]);
        float e3 = __builtin_amdgcn_exp2f(sc1[j][3]);
        rs += (e0 + e1) + (e2 + e3);
        uint2 pk;
        pk.x = cvt_pk_bf16(e0, e1);
        pk.y = cvt_pk_bf16(e2, e3);
        *(uint2*)(pw + ((c * 128 + 32 * j + 8 * g) ^ ((c & 7) << 4))) = pk;
      }
      l_run[1] += rs;
    }
    asm volatile("s_waitcnt lgkmcnt(0)" ::: "memory");
    __builtin_amdgcn_s_setprio(1);
#pragma unroll
    for (int ns = 0; ns < 2; ++ns) {
      s16x8 pa = *(const s16x8*)(pw + ((c * 128 + ns * 64 + g * 16) ^ ((c & 7) << 4)));
#pragma unroll
      for (int dj = 0; dj < 4; ++dj) {
        int row = 16 * dj + c;
        s16x8 vb = *(const s16x8*)(sV[cur] + ((row * 128 + ns * 64 + g * 16) ^ ((c & 7) << 4)));
        o_acc[1][dj] = __builtin_amdgcn_mfma_f32_16x16x32_bf16(pa, vb, o_acc[1][dj], 0, 0, 0);
      }
    }
    __builtin_amdgcn_s_setprio(0);
    asm volatile("" ::: "memory");   // keep next-iter P writes below these pa reads
  }

  // epilogue: reduce lane-partial l across g-groups, normalize, store ctx bf16
  const int b = bh >> 4, h = bh & 15;
#pragma unroll
  for (int u = 0; u < 2; ++u) {
    float l = l_run[u];
    l += __shfl_xor(l, 16);
    l += __shfl_xor(l, 32);
#pragma unroll
    for (int r = 0; r < 4; ++r) {
      float lr = __shfl(l, (lane & 48) | (4 * g + r));
      float inv = 1.f / lr;
      int srow = q0 + 32 * w + 16 * u + 4 * g + r;
      unsigned short* crow = Ctx + ((size_t)(b * 2048 + srow)) * 1024 + h * 64;
#pragma unroll
      for (int dj = 0; dj < 4; ++dj)
        crow[16 * dj + c] = f2bf(o_acc[u][dj][r] * inv);
    }
  }
}

extern "C" void kernel_launch(void* const* d_in, const int* in_sizes, int n_in,
                              void* d_out, int out_size, void* d_ws, size_t ws_size,
                              hipStream_t stream) {
  const float* hidden = (const float*)d_in[0];   // (4,2048,1024) f32
  const int*   pos    = (const int*)d_in[1];     // (4,2048) i32
  const float* wqkv   = (const float*)d_in[2];   // (3072,1024) f32
  const float* wo     = (const float*)d_in[3];   // (1024,1024) f32

  char* ws = (char*)d_ws;
  unsigned short* hbf  = (unsigned short*)(ws);                 // 16,777,216 B
  unsigned short* wqbf = (unsigned short*)(ws + 16777216);      //  6,291,456
  unsigned short* wobf = (unsigned short*)(ws + 23068672);      //  2,097,152
  unsigned short* vbuf = (unsigned short*)(ws + 25165824);      // 16,777,216
  unsigned short* Qr   = (unsigned short*)(ws + 41943040);      // 16,777,216
  unsigned short* Kr   = (unsigned short*)(ws + 58720256);      // 16,777,216
  unsigned short* Vt   = (unsigned short*)(ws + 75497472);      // 16,777,216
  unsigned short* ctx  = (unsigned short*)(ws + 92274688);      // 16,777,216
  float*          ctab = (float*)(ws + 109051904);              //  1,048,576
  float*          stab = (float*)(ws + 110100480);              //  1,048,576
  // total: 111,149,056 B

  cvt_all_kernel<<<12288, 256, 0, stream>>>(hidden, wqkv, wo, hbf, wqbf, wobf);
  rope_table_kernel<<<1024, 256, 0, stream>>>(pos, ctab, stab);

  dim3 gq(64, 24);
  gemm_bt_kernel<2><<<gq, 256, 0, stream>>>(hbf, wqbf, nullptr, 3072, 1024,
                                            ctab, stab, Qr, Kr, vbuf);

  vtrans_kernel<<<2048, 256, 0, stream>>>(vbuf, Vt);

  dim3 ga(16, 64);
  attn_kernel<<<ga, 256, 0, stream>>>(Qr, Kr, Vt, ctx);

  dim3 go(64, 8);
  gemm_bt_kernel<1><<<go, 256, 0, stream>>>(ctx, wobf, d_out, 1024, 1024,
                                            nullptr, nullptr, nullptr, nullptr, nullptr);
}

// Round 6
// 211.842 us; speedup vs baseline: 1.3633x; 1.0068x over previous
//
#include <hip/hip_runtime.h>
#include <hip/hip_bf16.h>

// ModernBertAttention: B=4 S=2048 H=1024 NH=16 HD=64, rope theta=160000, f32 in/out.
// R6: attn rewritten on 32x32x16 MFMA: wave owns 32 q-cols x 64 kv; P stays in
//     registers (cvt_pk + v_permlane32_swap relayout, T12) -> no sP, 16 ds_reads/iter
//     (was 28). LDS 32KB. Fixed m=0 exp2 softmax. GEMMs/vtrans unchanged from R5.

#define GLOBAL_AS __attribute__((address_space(1)))
#define LDS_AS    __attribute__((address_space(3)))

using f32x4  = __attribute__((ext_vector_type(4))) float;
using f32x16 = __attribute__((ext_vector_type(16))) float;
using s16x8  = __attribute__((ext_vector_type(8))) short;

__device__ __forceinline__ void gld_lds16(const void* g, void* l) {
  __builtin_amdgcn_global_load_lds((const GLOBAL_AS void*)g, (LDS_AS void*)l, 16, 0, 0);
}

__device__ __forceinline__ unsigned short f2bf(float f) {
  unsigned int u = __float_as_uint(f);
  u = (u + 0x7fffu + ((u >> 16) & 1u)) >> 16;   // RNE
  return (unsigned short)u;
}
__device__ __forceinline__ unsigned int cvt_pk_bf16(float lo, float hi) {
  unsigned int r;
  asm("v_cvt_pk_bf16_f32 %0, %1, %2" : "=v"(r) : "v"(lo), "v"(hi));
  return r;
}
// swap hi32 lanes of a with lo32 lanes of b: a' = lo(a)||lo(b), b' = hi(a)||hi(b)
__device__ __forceinline__ void pswap(unsigned int& a, unsigned int& b) {
  asm("v_permlane32_swap_b32 %0, %1" : "+v"(a), "+v"(b));
}

// ---------------- merged f32 -> bf16 convert (4 elems/thread) ----------------
__global__ __launch_bounds__(256) void cvt_all_kernel(const float* __restrict__ h,
                                                      const float* __restrict__ wq,
                                                      const float* __restrict__ wo,
                                                      unsigned short* __restrict__ hb,
                                                      unsigned short* __restrict__ wqb,
                                                      unsigned short* __restrict__ wob) {
  int b = blockIdx.x;
  const float* src; unsigned short* dst; int i;
  if (b < 8192)       { src = h;  dst = hb;  i = b * 256 + threadIdx.x; }
  else if (b < 11264) { src = wq; dst = wqb; i = (b - 8192) * 256 + threadIdx.x; }
  else                { src = wo; dst = wob; i = (b - 11264) * 256 + threadIdx.x; }
  float4 v = ((const float4*)src)[i];
  ushort4 o;
  o.x = f2bf(v.x); o.y = f2bf(v.y); o.z = f2bf(v.z); o.w = f2bf(v.w);
  ((ushort4*)dst)[i] = o;
}

// ---------------- rope cos/sin table: idx = (b*2048+s)*32 + d ----------------
__global__ __launch_bounds__(256) void rope_table_kernel(const int* __restrict__ pos,
                                                         float* __restrict__ ctab,
                                                         float* __restrict__ stab) {
  int idx = blockIdx.x * 256 + threadIdx.x;   // B*S*32 total
  int d = idx & 31;
  int bs = idx >> 5;
  float p = (float)pos[bs];
  float inv = exp2f(-(float)d * 0.5402410118609203f);  // theta^(-d/32)
  float f = p * inv;
  ctab[idx] = cosf(f);
  stab[idx] = sinf(f);
}

// ---------------- GEMM C[m,n] = sum_k A[m,k]*B[n,k], bf16 in, 128x128 tile, BK=64 ----------------
// MODE 1: f32 C store. MODE 2: fused QKV epilogue (rope -> Qr/Kr, V -> vbuf).
template<int MODE>
__global__ __launch_bounds__(256) void gemm_bt_kernel(const unsigned short* __restrict__ A,
                                                      const unsigned short* __restrict__ Bm,
                                                      void* __restrict__ C, int N, int K,
                                                      const float* __restrict__ ctab,
                                                      const float* __restrict__ stab,
                                                      unsigned short* __restrict__ Qr,
                                                      unsigned short* __restrict__ Kr,
                                                      unsigned short* __restrict__ vbuf) {
  __shared__ char sA[16384];   // 128 rows x 64 bf16 (128B rows), XOR-swizzled (row&7)<<4
  __shared__ char sB[16384];
  const int tid  = threadIdx.x;
  const int lane = tid & 63, w = tid >> 6;
  const int g = lane >> 4, c = lane & 15;
  const int wr = w >> 1, wc = w & 1;
  const int m0 = blockIdx.x * 128, n0 = blockIdx.y * 128;
  const char* Ab = (const char*)A;
  const char* Bb = (const char*)Bm;

  f32x4 acc[4][4] = {};
  for (int k0 = 0; k0 < K; k0 += 64) {
    __syncthreads();
#pragma unroll
    for (int rr = 0; rr < 4; ++rr) {
      int o = tid * 16 + rr * 4096;
      int row = o >> 7;
      int col = (o & 127) ^ ((row & 7) << 4);   // pre-swizzled source column
      gld_lds16(Ab + ((size_t)(m0 + row) * K + k0) * 2 + col, sA + o);
      gld_lds16(Bb + ((size_t)(n0 + row) * K + k0) * 2 + col, sB + o);
    }
    __syncthreads();
#pragma unroll
    for (int ks = 0; ks < 2; ++ks) {
      s16x8 af[4], bfr[4];
#pragma unroll
      for (int i = 0; i < 4; ++i) {
        int row = 64 * wr + 16 * i + c;
        af[i] = *(const s16x8*)(sA + ((row * 128 + ks * 64 + g * 16) ^ ((row & 7) << 4)));
      }
#pragma unroll
      for (int j = 0; j < 4; ++j) {
        int row = 64 * wc + 16 * j + c;
        bfr[j] = *(const s16x8*)(sB + ((row * 128 + ks * 64 + g * 16) ^ ((row & 7) << 4)));
      }
#pragma unroll
      for (int i = 0; i < 4; ++i)
#pragma unroll
        for (int j = 0; j < 4; ++j)
          acc[i][j] = __builtin_amdgcn_mfma_f32_16x16x32_bf16(af[i], bfr[j], acc[i][j], 0, 0, 0);
    }
  }

  if (MODE == 1) {
#pragma unroll
    for (int i = 0; i < 4; ++i)
#pragma unroll
      for (int j = 0; j < 4; ++j)
#pragma unroll
        for (int r = 0; r < 4; ++r) {
          int m = m0 + 64 * wr + 16 * i + 4 * g + r;
          int n = n0 + 64 * wc + 16 * j + c;
          ((float*)C)[(size_t)m * N + n] = acc[i][j][r];
        }
  } else {
    const int t = blockIdx.y;   // 0..7 Q, 8..15 K, 16..23 V
    if (t < 16) {
      unsigned short* dstb = (t < 8) ? Qr : Kr;
      const float qs = (t < 8) ? 0.18033688011112042f : 1.0f;  // SCALE*log2(e) on Q
      const int h = 2 * (t & 7) + wc;
#pragma unroll
      for (int i = 0; i < 4; ++i)
#pragma unroll
        for (int r = 0; r < 4; ++r) {
          int m = m0 + 64 * wr + 16 * i + 4 * g + r;
          int b = m >> 11, s = m & 2047;
          unsigned short* drow = dstb + ((size_t)(b * 16 + h) * 2048 + s) * 64;
#pragma unroll
          for (int j = 0; j < 2; ++j) {
            int d = 16 * j + c;
            float co = ctab[(size_t)m * 32 + d];
            float si = stab[(size_t)m * 32 + d];
            float x1 = acc[i][j][r], x2 = acc[i][j + 2][r];
            drow[d]      = f2bf((x1 * co - x2 * si) * qs);
            drow[d + 32] = f2bf((x2 * co + x1 * si) * qs);
          }
        }
    } else {
#pragma unroll
      for (int i = 0; i < 4; ++i)
#pragma unroll
        for (int j = 0; j < 4; ++j)
#pragma unroll
          for (int r = 0; r < 4; ++r) {
            int m = m0 + 64 * wr + 16 * i + 4 * g + r;
            int n = (t - 16) * 128 + 64 * wc + 16 * j + c;
            vbuf[(size_t)m * 1024 + n] = f2bf(acc[i][j][r]);
          }
    }
  }
}

// ---------------- V transpose: vbuf (B*S,1024) -> Vt (B,NH,64,S) ----------------
__global__ __launch_bounds__(256) void vtrans_kernel(const unsigned short* __restrict__ vbuf,
                                                     unsigned short* __restrict__ Vt) {
  __shared__ unsigned short tile[64][80];
  int bid = blockIdx.x;                      // b*16*32 + h*32 + st
  int st = bid & 31, h = (bid >> 5) & 15, b = bid >> 9;
  int s0 = st * 64;
  int t = threadIdx.x;
  {
    int row = t >> 2, part = t & 3;
    const unsigned short* src = vbuf + ((size_t)(b * 2048 + s0 + row)) * 1024 + h * 64 + part * 16;
    uint4 v0 = *(const uint4*)(src);
    uint4 v1 = *(const uint4*)(src + 8);
    *(uint4*)&tile[row][part * 16]     = v0;
    *(uint4*)&tile[row][part * 16 + 8] = v1;
  }
  __syncthreads();
  {
    int d = t >> 2, sp = t & 3;
    unsigned short vals[16];
#pragma unroll
    for (int i = 0; i < 16; ++i) vals[i] = tile[sp * 16 + i][d];
    unsigned short* dst = Vt + ((size_t)(b * 16 + h) * 64 + d) * 2048 + s0 + sp * 16;
    *(uint4*)(dst)     = ((const uint4*)vals)[0];
    *(uint4*)(dst + 8) = ((const uint4*)vals)[1];
  }
}

// ---------------- flash attention: 128 q/block, 4 waves, 32x32x16 MFMA ----------------
// Swapped QK^T: D[kv][q=lane&31]; P relayout in-register via cvt_pk + permlane32_swap;
// K/V^T double-buffered in LDS; fixed m=0 exp2 softmax; no P LDS buffer.
__global__ __launch_bounds__(256) void attn_kernel(const unsigned short* __restrict__ Q,
                                                   const unsigned short* __restrict__ Kr,
                                                   const unsigned short* __restrict__ Vt,
                                                   unsigned short* __restrict__ Ctx) {
  __shared__ char sK[2][8192];   // 64 kv rows x 128B, swizzle (row&7)<<4
  __shared__ char sV[2][8192];   // 64 d rows x 128B (V^T tile)
  const int tid  = threadIdx.x;
  const int lane = tid & 63, w = tid >> 6;
  const int hi = lane >> 5, ql = lane & 31;
  const int swz = (ql & 7) << 4;
  // XCD-chunked swizzle: each XCD owns 8 consecutive bh (K+V ~4MB = one L2)
  int lin = blockIdx.x + 16 * blockIdx.y;            // grid (16, 64)
  int eff = (lin & 7) * 128 + (lin >> 3);
  const int bh = eff >> 4;
  const int q0 = (eff & 15) * 128;
  const char* kh = (const char*)(Kr + (size_t)bh * 2048 * 64);
  const char* vh = (const char*)(Vt + (size_t)bh * 64 * 2048);

  // Q B-frags: qf[t] holds Q[q=q0+32w+ql][d = t*16 + hi*8 .. +7]
  s16x8 qf[4];
  {
    const char* qrow = (const char*)Q + ((size_t)bh * 2048 + q0 + 32 * w + ql) * 128;
#pragma unroll
    for (int t = 0; t < 4; ++t) qf[t] = *(const s16x8*)(qrow + t * 32 + hi * 16);
  }

  // prologue: stage K,V tile 0 into buffer 0
#pragma unroll
  for (int rr = 0; rr < 2; ++rr) {
    int o = tid * 16 + rr * 4096;
    int l = o ^ (((o >> 7) & 7) << 4);
    gld_lds16(kh + l, sK[0] + o);
    gld_lds16(vh + (size_t)(o >> 7) * 4096 + (l & 127), sV[0] + o);
  }

  float l_run = 0.f;
  f32x16 oa0 = {}, oa1 = {};   // D[d][q]: dblk 0 (d 0-31), dblk 1 (d 32-63)

  for (int it = 0; it < 32; ++it) {
    __syncthreads();   // K/V(it) resident (vmcnt drained); other buffer free
    const int cur = it & 1;
    if (it + 1 < 32) {                   // stage K/V(it+1)
      int kvn = (it + 1) * 64;
#pragma unroll
      for (int rr = 0; rr < 2; ++rr) {
        int o = tid * 16 + rr * 4096;
        int l = o ^ (((o >> 7) & 7) << 4);
        gld_lds16(kh + (size_t)kvn * 128 + l, sK[cur ^ 1] + o);
        gld_lds16(vh + (size_t)(o >> 7) * 4096 + kvn * 2 + (l & 127), sV[cur ^ 1] + o);
      }
    }

    // QK^T swapped: sc0 = S^T[kv 0-31][q], sc1 = S^T[kv 32-63][q]
    f32x16 sc0 = {}, sc1 = {};
    __builtin_amdgcn_s_setprio(1);
#pragma unroll
    for (int t = 0; t < 4; ++t) {
      int cx = (t * 32 + hi * 16) ^ swz;
      s16x8 k0 = *(const s16x8*)(sK[cur] + ql * 128 + cx);
      s16x8 k1 = *(const s16x8*)(sK[cur] + (32 + ql) * 128 + cx);
      sc0 = __builtin_amdgcn_mfma_f32_32x32x16_bf16(k0, qf[t], sc0, 0, 0, 0);
      sc1 = __builtin_amdgcn_mfma_f32_32x32x16_bf16(k1, qf[t], sc1, 0, 0, 0);
    }
    __builtin_amdgcn_s_setprio(0);

    // softmax (fixed m=0): p = exp2(s), lane-partial row sum
    float rs = 0.f;
#pragma unroll
    for (int r = 0; r < 16; ++r) { sc0[r] = __builtin_amdgcn_exp2f(sc0[r]); rs += sc0[r]; }
#pragma unroll
    for (int r = 0; r < 16; ++r) { sc1[r] = __builtin_amdgcn_exp2f(sc1[r]); rs += sc1[r]; }
    l_run += rs;

    // P -> PV B-frags in-register: per 32-kv block, pairs + permlane32_swap
    // sc reg r holds kv=(r&3)+8*(r>>2)+4*hi; B-frag step ss needs kv=ss*16+hi*8+i
    unsigned int bp[16];
#pragma unroll
    for (int blk = 0; blk < 2; ++blk) {
      const f32x16& s = blk ? sc1 : sc0;
      unsigned int a0 = cvt_pk_bf16(s[0],  s[1]);    // (kv0,1)|(4,5)
      unsigned int a1 = cvt_pk_bf16(s[2],  s[3]);    // (2,3)|(6,7)
      unsigned int a2 = cvt_pk_bf16(s[4],  s[5]);    // (8,9)|(12,13)
      unsigned int a3 = cvt_pk_bf16(s[6],  s[7]);    // (10,11)|(14,15)
      pswap(a0, a2); pswap(a1, a3);
      bp[blk * 8 + 0] = a0; bp[blk * 8 + 1] = a1;    // step blk*2:   kv blk*32+0..15
      bp[blk * 8 + 2] = a2; bp[blk * 8 + 3] = a3;
      unsigned int b0 = cvt_pk_bf16(s[8],  s[9]);    // (16,17)|(20,21)
      unsigned int b1 = cvt_pk_bf16(s[10], s[11]);
      unsigned int b2 = cvt_pk_bf16(s[12], s[13]);   // (24,25)|(28,29)
      unsigned int b3 = cvt_pk_bf16(s[14], s[15]);
      pswap(b0, b2); pswap(b1, b3);
      bp[blk * 8 + 4] = b0; bp[blk * 8 + 5] = b1;    // step blk*2+1: kv blk*32+16..31
      bp[blk * 8 + 6] = b2; bp[blk * 8 + 7] = b3;
    }

    // PV: oa[dblk] += V^T[d][kv] * P^T[kv][q]
    __builtin_amdgcn_s_setprio(1);
#pragma unroll
    for (int ss = 0; ss < 4; ++ss) {
      uint4 u = {bp[ss * 4], bp[ss * 4 + 1], bp[ss * 4 + 2], bp[ss * 4 + 3]};
      s16x8 pb = __builtin_bit_cast(s16x8, u);
      int cx = (ss * 32 + hi * 16) ^ swz;
      s16x8 v0 = *(const s16x8*)(sV[cur] + ql * 128 + cx);
      s16x8 v1 = *(const s16x8*)(sV[cur] + (32 + ql) * 128 + cx);
      oa0 = __builtin_amdgcn_mfma_f32_32x32x16_bf16(v0, pb, oa0, 0, 0, 0);
      oa1 = __builtin_amdgcn_mfma_f32_32x32x16_bf16(v1, pb, oa1, 0, 0, 0);
    }
    __builtin_amdgcn_s_setprio(0);
  }

  // epilogue: partner lane (same q, other kv half) sum, normalize, store
  l_run += __shfl_xor(l_run, 32);
  float inv = 1.f / l_run;
  const int b = bh >> 4, h = bh & 15;
  const int q = q0 + 32 * w + ql;
  unsigned short* crow = Ctx + ((size_t)(b * 2048 + q)) * 1024 + h * 64;
#pragma unroll
  for (int dblk = 0; dblk < 2; ++dblk) {
    const f32x16& oa = dblk ? oa1 : oa0;
#pragma unroll
    for (int grp = 0; grp < 4; ++grp) {
      ushort4 st;
      st.x = f2bf(oa[4 * grp + 0] * inv);
      st.y = f2bf(oa[4 * grp + 1] * inv);
      st.z = f2bf(oa[4 * grp + 2] * inv);
      st.w = f2bf(oa[4 * grp + 3] * inv);
      *(ushort4*)(crow + dblk * 32 + 8 * grp + 4 * hi) = st;
    }
  }
}

extern "C" void kernel_launch(void* const* d_in, const int* in_sizes, int n_in,
                              void* d_out, int out_size, void* d_ws, size_t ws_size,
                              hipStream_t stream) {
  const float* hidden = (const float*)d_in[0];   // (4,2048,1024) f32
  const int*   pos    = (const int*)d_in[1];     // (4,2048) i32
  const float* wqkv   = (const float*)d_in[2];   // (3072,1024) f32
  const float* wo     = (const float*)d_in[3];   // (1024,1024) f32

  char* ws = (char*)d_ws;
  unsigned short* hbf  = (unsigned short*)(ws);                 // 16,777,216 B
  unsigned short* wqbf = (unsigned short*)(ws + 16777216);      //  6,291,456
  unsigned short* wobf = (unsigned short*)(ws + 23068672);      //  2,097,152
  unsigned short* vbuf = (unsigned short*)(ws + 25165824);      // 16,777,216
  unsigned short* Qr   = (unsigned short*)(ws + 41943040);      // 16,777,216
  unsigned short* Kr   = (unsigned short*)(ws + 58720256);      // 16,777,216
  unsigned short* Vt   = (unsigned short*)(ws + 75497472);      // 16,777,216
  unsigned short* ctx  = (unsigned short*)(ws + 92274688);      // 16,777,216
  float*          ctab = (float*)(ws + 109051904);              //  1,048,576
  float*          stab = (float*)(ws + 110100480);              //  1,048,576
  // total: 111,149,056 B

  cvt_all_kernel<<<12288, 256, 0, stream>>>(hidden, wqkv, wo, hbf, wqbf, wobf);
  rope_table_kernel<<<1024, 256, 0, stream>>>(pos, ctab, stab);

  dim3 gq(64, 24);
  gemm_bt_kernel<2><<<gq, 256, 0, stream>>>(hbf, wqbf, nullptr, 3072, 1024,
                                            ctab, stab, Qr, Kr, vbuf);

  vtrans_kernel<<<2048, 256, 0, stream>>>(vbuf, Vt);

  dim3 ga(16, 64);
  attn_kernel<<<ga, 256, 0, stream>>>(Qr, Kr, Vt, ctx);

  dim3 go(64, 8);
  gemm_bt_kernel<1><<<go, 256, 0, stream>>>(ctx, wobf, d_out, 1024, 1024,
                                            nullptr, nullptr, nullptr, nullptr, nullptr);
}